// Round 3
// baseline (11971.471 us; speedup 1.0000x reference)
//
#include <hip/hip_runtime.h>
#include <hip/hip_cooperative_groups.h>
#include <stdint.h>

namespace cg = cooperative_groups;

typedef unsigned short us;
typedef __attribute__((ext_vector_type(8))) short bf16x8;
typedef __attribute__((ext_vector_type(4))) float f32x4;

#define DI __device__ __forceinline__

constexpr int LS = 48, LT = 48, NB = 64, E = 512, G = 2048, V = 32000;
constexpr int TD = LT - 1;       // 47 decoder steps
constexpr int MENC = LS * NB;    // 3072
constexpr int MDEC = TD * NB;    // 3008
constexpr int NCB = V / 64;      // 500 column blocks for logits stats

DI float bf2f(us u) { union { unsigned int i; float f; } c; c.i = ((unsigned int)u) << 16; return c.f; }
DI us f2bf(float f) { union { float f; unsigned int i; } c; c.f = f; return (us)((c.i + 0x7fffu + ((c.i >> 16) & 1u)) >> 16); }
DI float sigm(float x) { return 1.f / (1.f + __expf(-x)); }
DI float tanh_(float x) { x = fminf(15.f, fmaxf(-15.f, x)); float e = __expf(2.f * x); return (e - 1.f) / (e + 1.f); }

// ---------------- utility kernels ----------------
__global__ __launch_bounds__(256) void zero_k(float* p, int n) {
    int i = blockIdx.x * 256 + threadIdx.x;
    if (i < n) p[i] = 0.f;
}

__global__ __launch_bounds__(256) void conv_bf16(const float* __restrict__ src, int lds, int coff,
                                                 us* __restrict__ dst, int rows, int cols) {
    int i = blockIdx.x * 256 + threadIdx.x;
    if (i >= rows * cols) return;
    int r = i / cols, c = i % cols;
    dst[i] = f2bf(src[(size_t)r * lds + coff + c]);
}

__global__ __launch_bounds__(256) void gather_bf16(const int* __restrict__ idx, const float* __restrict__ emb,
                                                   us* __restrict__ dst) {
    int r = blockIdx.x;
    int id = idx[r];
    const float* s = emb + (size_t)id * E;
    us* d = dst + (size_t)r * E;
    for (int c = threadIdx.x; c < E; c += 256) d[c] = f2bf(s[c]);
}

// permuted bf16 pack: out[(j*4+g)][c] ; c<512 -> Wih[g*512+j][512+c], else Whh[g*512+j][c-512]
__global__ __launch_bounds__(256) void pack_wcomb_bf(const float* __restrict__ Wih, const float* __restrict__ Whh,
                                                     us* __restrict__ out) {
    int i = blockIdx.x * 256 + threadIdx.x;  // 2048*1024
    int rp = i >> 10, c = i & 1023;
    int j = rp >> 2, g = rp & 3;
    int orig = g * 512 + j;
    float v = (c < 512) ? Wih[(size_t)orig * 1024 + 512 + c] : Whh[(size_t)orig * 512 + (c - 512)];
    out[i] = f2bf(v);
}

// permuted bf16 pack: out[(j*4+g)][c] = Whh[g*512+j][c]
__global__ __launch_bounds__(256) void pack_whh_bf(const float* __restrict__ Whh, us* __restrict__ out) {
    int i = blockIdx.x * 256 + threadIdx.x;  // 2048*512
    int rp = i >> 9, c = i & 511;
    int j = rp >> 2, g = rp & 3;
    out[i] = f2bf(Whh[(size_t)(g * 512 + j) * 512 + c]);
}

// ---------------- bf16 MFMA GEMM: C[M][N] = A[M][K] @ W[N][K]^T (+bias) ----------------
template <int EPI>
__global__ __launch_bounds__(256) void gemm16(const us* __restrict__ A, int lda,
                                              const us* __restrict__ W, int ldw,
                                              const float* __restrict__ b1, const float* __restrict__ b2,
                                              void* __restrict__ outp, int ldc, int K, int Mrows) {
    __shared__ us As[64][40];
    __shared__ us Ws[64][40];
    const int tid = threadIdx.x;
    const int m0 = blockIdx.y << 6, n0 = blockIdx.x << 6;
    const int srow = tid >> 2, sk = (tid & 3) << 3;
    const int l = tid & 63, w = tid >> 6;
    const int la = l & 15, lb = l >> 4;
    f32x4 acc[4] = {};
    const us* Aptr = A + (size_t)(m0 + srow) * lda + sk;
    const us* Wptr = W + (size_t)(n0 + srow) * ldw + sk;
    for (int k0 = 0; k0 < K; k0 += 32) {
        *(uint4*)&As[srow][sk] = *(const uint4*)(Aptr + k0);
        *(uint4*)&Ws[srow][sk] = *(const uint4*)(Wptr + k0);
        __syncthreads();
        bf16x8 af = *(bf16x8*)&As[(w << 4) + la][lb << 3];
#pragma unroll
        for (int c = 0; c < 4; c++) {
            bf16x8 bw = *(bf16x8*)&Ws[(c << 4) + la][lb << 3];
            acc[c] = __builtin_amdgcn_mfma_f32_16x16x32_bf16(af, bw, acc[c], 0, 0, 0);
        }
        __syncthreads();
    }
    if (EPI == 1) {
        us* O = (us*)outp;
#pragma unroll
        for (int c = 0; c < 4; c++) {
            int col = n0 + (c << 4) + la;
            float badd = (b1 ? b1[col] : 0.f) + (b2 ? b2[col] : 0.f);
#pragma unroll
            for (int r = 0; r < 4; r++) {
                int row = m0 + (w << 4) + (lb << 2) + r;
                O[(size_t)row * ldc + col] = f2bf(acc[c][r] + badd);
            }
        }
    } else {
        float* S = (float*)outp;
        float x[4][4];
#pragma unroll
        for (int c = 0; c < 4; c++) {
            int col = n0 + (c << 4) + la;
            float badd = b1[col];
#pragma unroll
            for (int r = 0; r < 4; r++) x[c][r] = acc[c][r] + badd;
        }
#pragma unroll
        for (int r = 0; r < 4; r++) {
            float lm = fmaxf(fmaxf(x[0][r], x[1][r]), fmaxf(x[2][r], x[3][r]));
#pragma unroll
            for (int mk = 1; mk < 16; mk <<= 1) lm = fmaxf(lm, __shfl_xor(lm, mk));
            float ls = __expf(x[0][r] - lm) + __expf(x[1][r] - lm) + __expf(x[2][r] - lm) + __expf(x[3][r] - lm);
#pragma unroll
            for (int mk = 1; mk < 16; mk <<= 1) ls += __shfl_xor(ls, mk);
            if (la == 0) {
                int row = m0 + (w << 4) + (lb << 2) + r;
                size_t o = ((size_t)blockIdx.x * Mrows + row) * 2;
                S[o] = lm;
                S[o + 1] = ls;
            }
        }
    }
}

// ---------------- persistent encoder: Whh fragments in registers, 1 sync/step ----------------
// grid 256: dir = bx>>7, lbx = bx&127: block owns 4 j (16 permuted gate rows), all 64 b.
__global__ __launch_bounds__(256, 1) void enc_coop2(const us* __restrict__ gxf, const us* __restrict__ gxb,
                                                    const us* __restrict__ whhf_p, const us* __restrict__ whhb_p,
                                                    us* __restrict__ hA, us* __restrict__ hB,
                                                    us* __restrict__ hs_bf) {
    cg::grid_group gg = cg::this_grid();
    const int bx = blockIdx.x, tid = threadIdx.x;
    const int dir = bx >> 7, lbx = bx & 127;
    const int n0 = lbx * 16, j0 = lbx * 4;
    const us* gx = dir ? gxb : gxf;
    const us* whp = dir ? whhb_p : whhf_p;
    const int l = tid & 63, w = tid >> 6;
    const int arow = w * 16 + (l & 15);
    const int koff = (l >> 4) * 8;
    __shared__ float gbuf[64 * 17];
    bf16x8 wfrag[16];
#pragma unroll
    for (int k0 = 0; k0 < 16; ++k0)
        wfrag[k0] = *(const bf16x8*)&whp[(size_t)(n0 + (l & 15)) * 512 + k0 * 32 + koff];
    const int cb = tid & 63, cjj = tid >> 6;
    const int j = j0 + cjj;
    float cstate = 0.f;
    const size_t dof = (size_t)dir * NB * 512;
    for (int s = 0; s < LS; ++s) {
        const us* hprev = ((s & 1) ? hB : hA) + dof;
        us* hcur = (us*)(((s & 1) ? hA : hB) + dof);
        const int lrow = dir ? (LS - 1 - s) : s;
        f32x4 acc = {0.f, 0.f, 0.f, 0.f};
#pragma unroll
        for (int k0 = 0; k0 < 16; ++k0) {
            bf16x8 af = *(const bf16x8*)&hprev[(size_t)arow * 512 + k0 * 32 + koff];
            acc = __builtin_amdgcn_mfma_f32_16x16x32_bf16(af, wfrag[k0], acc, 0, 0, 0);
        }
#pragma unroll
        for (int r = 0; r < 4; ++r) gbuf[(w * 16 + (l >> 4) * 4 + r) * 17 + (l & 15)] = acc[r];
        __syncthreads();
        {
            const us* grow = gx + ((size_t)lrow * NB + cb) * G;
            float ai = gbuf[cb * 17 + cjj * 4 + 0] + bf2f(grow[j]);
            float af_ = gbuf[cb * 17 + cjj * 4 + 1] + bf2f(grow[512 + j]);
            float ag = gbuf[cb * 17 + cjj * 4 + 2] + bf2f(grow[1024 + j]);
            float ao = gbuf[cb * 17 + cjj * 4 + 3] + bf2f(grow[1536 + j]);
            float cn = sigm(af_) * cstate + sigm(ai) * tanh_(ag);
            float hn = sigm(ao) * tanh_(cn);
            cstate = cn;
            us hb = f2bf(hn);
            hcur[(size_t)cb * 512 + j] = hb;
            hs_bf[((size_t)lrow * NB + cb) * 1024 + dir * 512 + j] = hb;
        }
        __syncthreads();
        gg.sync();
    }
}

// ---------------- persistent decoder: all step-invariant data in LDS/registers ----------------
// grid 256. A-blocks (0..127): cell-MFMA (wcomb frags in regs) + context (hs slice in LDS).
// B-blocks (128..255): q (wq regs) + scores (hsproj slice LDS) + o (lin_W slice LDS).
__global__ __launch_bounds__(256, 1) void dec_coop2(
    const us* __restrict__ gemb, const us* __restrict__ wcomb_p,
    const float* __restrict__ attn_W, const float* __restrict__ attn_v,
    const us* __restrict__ hsproj, const us* __restrict__ hs_bf,
    const us* __restrict__ linw_bf, const float* __restrict__ lin_b,
    us* __restrict__ h0, us* __restrict__ h1,
    us* __restrict__ od_bf, float* __restrict__ qbuf,
    float* __restrict__ scores, us* __restrict__ ctx_bf,
    us* __restrict__ hdec_bf) {
    cg::grid_group gg = cg::this_grid();
    __shared__ __align__(16) char smem[111360];
    const int bx = blockIdx.x, tid = threadIdx.x;
    const int l = tid & 63, w = tid >> 6;
    const bool isA = bx < 128;

    // A-path LDS
    us* hs_s = (us*)smem;                         // [48*512]
    float* gbuf = (float*)(smem + 49152);         // [64*17]
    float* pls = (float*)(smem + 49152 + 4352);   // [48]
    // B-path LDS
    us* hsproj_s = (us*)smem;                     // [24*1032]
    us* linw_s = (us*)(smem + 49536);             // [4*1544]
    us* stage = (us*)(smem + 49536 + 12352);      // [32*520] or [16*1544]

    bf16x8 wfrag[32];
    float cstate = 0.f;
    float wqreg[16];
    float vv[16];
    float linb_reg = 0.f;
    const int bB = bx - 128;
    // A ids
    const int arow = w * 16 + (l & 15), koff = (l >> 4) * 8;
    const int n0A = bx * 16;
    const int cb = tid & 63, cjj = tid >> 6;
    const int jA = bx * 4 + cjj;
    // E ids
    const int eb = bx >> 1, edh = bx & 1;
    // B ids
    const int qn = tid >> 5, qkq = tid & 31;
    // C ids
    const int lgrp = bB >> 5, bpair = bB & 31;
    // F ids (kq in lane bits so shfl works; d = wave)
    const int fb = tid & 15, fkq = (tid >> 4) & 3, fd = tid >> 6;
    const int d0F = bB * 4;

    if (isA) {
#pragma unroll
        for (int k0 = 0; k0 < 32; ++k0)
            wfrag[k0] = *(const bf16x8*)&wcomb_p[(size_t)(n0A + (l & 15)) * 1024 + k0 * 32 + koff];
        for (int idx = tid; idx < 48 * 64; idx += 256) {
            int r = idx >> 6, c8 = (idx & 63) * 8;
            *(uint4*)&hs_s[r * 512 + c8] = *(const uint4*)&hs_bf[((size_t)r * NB + eb) * 1024 + edh * 512 + c8];
        }
    } else {
        for (int idx = tid; idx < 24 * 128; idx += 256) {
            int r = idx >> 7, c8 = (idx & 127) * 8;
            int lp = r >> 1, bp = r & 1;
            *(uint4*)&hsproj_s[r * 1032 + c8] =
                *(const uint4*)&hsproj[((size_t)(lgrp * 12 + lp) * NB + (bpair * 2 + bp)) * 1024 + c8];
        }
        for (int idx = tid; idx < 4 * 192; idx += 256) {
            int r = idx / 192, c8 = (idx % 192) * 8;
            *(uint4*)&linw_s[r * 1544 + c8] = *(const uint4*)&linw_bf[(size_t)(d0F + r) * 1536 + c8];
        }
#pragma unroll
        for (int m = 0; m < 4; ++m)
            *(float4*)&wqreg[m * 4] = *(const float4*)&attn_W[(size_t)(bB * 8 + qn) * 1536 + qkq * 4 + m * 128];
#pragma unroll
        for (int m = 0; m < 4; ++m)
            *(float4*)&vv[m * 4] = *(const float4*)&attn_v[l * 4 + m * 256];
        linb_reg = lin_b[d0F + fd];
    }
    __syncthreads();

    for (int t = 0; t < TD; ++t) {
        const us* hprev = (t & 1) ? h1 : h0;
        us* hcur = (t & 1) ? h0 : h1;
        // ---- phase A: LSTM cell via MFMA (A-blocks) ----
        if (isA) {
            f32x4 acc = {0.f, 0.f, 0.f, 0.f};
#pragma unroll
            for (int k0 = 0; k0 < 32; ++k0) {
                const us* src = (k0 < 16) ? od_bf : hprev;
                int kk = (k0 & 15) * 32;
                bf16x8 af = *(const bf16x8*)&src[(size_t)arow * 512 + kk + koff];
                acc = __builtin_amdgcn_mfma_f32_16x16x32_bf16(af, wfrag[k0], acc, 0, 0, 0);
            }
#pragma unroll
            for (int r = 0; r < 4; ++r) gbuf[(w * 16 + (l >> 4) * 4 + r) * 17 + (l & 15)] = acc[r];
            __syncthreads();
            {
                const us* grow = gemb + ((size_t)t * NB + cb) * G;
                float ai = gbuf[cb * 17 + cjj * 4 + 0] + bf2f(grow[jA]);
                float af_ = gbuf[cb * 17 + cjj * 4 + 1] + bf2f(grow[512 + jA]);
                float ag = gbuf[cb * 17 + cjj * 4 + 2] + bf2f(grow[1024 + jA]);
                float ao = gbuf[cb * 17 + cjj * 4 + 3] + bf2f(grow[1536 + jA]);
                float cn = sigm(af_) * cstate + sigm(ai) * tanh_(ag);
                float hn = sigm(ao) * tanh_(cn);
                cstate = cn;
                us hb = f2bf(hn);
                hcur[(size_t)cb * 512 + jA] = hb;
                hdec_bf[((size_t)t * NB + cb) * 512 + jA] = hb;
            }
            __syncthreads();
        }
        gg.sync();
        if (t == TD - 1) break;
        // ---- phase B: q = h @ Wq^T (B-blocks) ----
        if (!isA) {
            for (int tile = 0; tile < 2; ++tile) {
                for (int idx = tid; idx < 32 * 64; idx += 256) {
                    int r = idx >> 6, c8 = (idx & 63) * 8;
                    *(uint4*)&stage[r * 520 + c8] = *(const uint4*)&hcur[(size_t)(tile * 32 + r) * 512 + c8];
                }
                __syncthreads();
                for (int b = 0; b < 32; ++b) {
                    float acc = 0.f;
#pragma unroll
                    for (int m = 0; m < 4; ++m) {
                        ushort4 hv = *(const ushort4*)&stage[b * 520 + qkq * 4 + m * 128];
                        acc += wqreg[m * 4 + 0] * bf2f(hv.x) + wqreg[m * 4 + 1] * bf2f(hv.y)
                             + wqreg[m * 4 + 2] * bf2f(hv.z) + wqreg[m * 4 + 3] * bf2f(hv.w);
                    }
#pragma unroll
                    for (int mk = 1; mk < 32; mk <<= 1) acc += __shfl_xor(acc, mk);
                    if (qkq == 0) qbuf[(size_t)(tile * 32 + b) * 1024 + bB * 8 + qn] = acc;
                }
                __syncthreads();
            }
        }
        gg.sync();
        // ---- phase C: scores (B-blocks) ----
        if (!isA) {
            float qv[2][16];
#pragma unroll
            for (int bp = 0; bp < 2; ++bp)
#pragma unroll
                for (int m = 0; m < 4; ++m)
                    *(float4*)&qv[bp][m * 4] = *(const float4*)&qbuf[(size_t)(bpair * 2 + bp) * 1024 + l * 4 + m * 256];
            for (int pi = 0; pi < 6; ++pi) {
                int pr = w * 6 + pi;
                int lp = pr >> 1, bp = pr & 1;
                float p = 0.f;
#pragma unroll
                for (int m = 0; m < 4; ++m) {
                    ushort4 hv = *(const ushort4*)&hsproj_s[pr * 1032 + l * 4 + m * 256];
                    p += vv[m * 4 + 0] * tanh_(bf2f(hv.x) + qv[bp][m * 4 + 0]);
                    p += vv[m * 4 + 1] * tanh_(bf2f(hv.y) + qv[bp][m * 4 + 1]);
                    p += vv[m * 4 + 2] * tanh_(bf2f(hv.z) + qv[bp][m * 4 + 2]);
                    p += vv[m * 4 + 3] * tanh_(bf2f(hv.w) + qv[bp][m * 4 + 3]);
                }
#pragma unroll
                for (int mk = 1; mk < 64; mk <<= 1) p += __shfl_xor(p, mk);
                if (l == 0) scores[(lgrp * 12 + lp) * 64 + bpair * 2 + bp] = p;
            }
        }
        gg.sync();
        // ---- phase E: softmax + context (A-blocks) ----
        if (isA) {
            if (tid < 64) {
                float x = (l < 48) ? scores[l * 64 + eb] : -1e30f;
                float mx = x;
#pragma unroll
                for (int mk = 1; mk < 64; mk <<= 1) mx = fmaxf(mx, __shfl_xor(mx, mk));
                float e = (l < 48) ? __expf(x - mx) : 0.f;
                float s = e;
#pragma unroll
                for (int mk = 1; mk < 64; mk <<= 1) s += __shfl_xor(s, mk);
                if (l < 48) pls[l] = e / s;
            }
            __syncthreads();
            float a0 = 0.f, a1 = 0.f;
            for (int li = 0; li < 48; ++li) {
                float pw = pls[li];
                unsigned int hv = *(const unsigned int*)&hs_s[li * 512 + tid * 2];
                a0 += pw * bf2f((us)(hv & 0xffffu));
                a1 += pw * bf2f((us)(hv >> 16));
            }
            unsigned int outw = (unsigned int)f2bf(a0) | ((unsigned int)f2bf(a1) << 16);
            *(unsigned int*)&ctx_bf[(size_t)eb * 1024 + edh * 512 + tid * 2] = outw;
            __syncthreads();
        }
        gg.sync();
        // ---- phase F: o = tanh([c;h] @ lin_W^T + b) (B-blocks) ----
        if (!isA) {
            for (int tile = 0; tile < 4; ++tile) {
                for (int idx = tid; idx < 16 * 192; idx += 256) {
                    int r = idx / 192, c8 = (idx % 192) * 8;
                    const us* src = (c8 < 1024) ? &ctx_bf[(size_t)(tile * 16 + r) * 1024 + c8]
                                                : &hcur[(size_t)(tile * 16 + r) * 512 + (c8 - 1024)];
                    *(uint4*)&stage[r * 1544 + c8] = *(const uint4*)src;
                }
                __syncthreads();
                float acc = 0.f;
#pragma unroll 8
                for (int m = 0; m < 96; ++m) {
                    int k = fkq * 4 + m * 16;
                    ushort4 hv = *(const ushort4*)&stage[fb * 1544 + k];
                    ushort4 wv = *(const ushort4*)&linw_s[fd * 1544 + k];
                    acc += bf2f(hv.x) * bf2f(wv.x) + bf2f(hv.y) * bf2f(wv.y)
                         + bf2f(hv.z) * bf2f(wv.z) + bf2f(hv.w) * bf2f(wv.w);
                }
                acc += __shfl_xor(acc, 16);
                acc += __shfl_xor(acc, 32);
                if (fkq == 0) {
                    float o = tanh_(acc + linb_reg);
                    od_bf[(size_t)(tile * 16 + fb) * 512 + d0F + fd] = f2bf(o);
                }
                __syncthreads();
            }
        }
        gg.sync();
    }
}

// ---------------- target logit: one wave per (t,b) row ----------------
__global__ __launch_bounds__(256) void tgt_kernel(const us* __restrict__ hdec_bf, const us* __restrict__ woutbf,
                                                  const float* __restrict__ out_b, const int* __restrict__ ts,
                                                  float* __restrict__ tgt) {
    int wid = blockIdx.x * 4 + (threadIdx.x >> 6);
    int l = threadIdx.x & 63;
    int t = wid >> 6, b = wid & 63;
    int tg = ts[(t + 1) * NB + b];
    const us* hr = hdec_bf + (size_t)wid * 512 + l * 8;
    const us* wr = woutbf + (size_t)tg * 512 + l * 8;
    float acc = 0.f;
#pragma unroll
    for (int i = 0; i < 8; i++) acc += bf2f(hr[i]) * bf2f(wr[i]);
#pragma unroll
    for (int m = 1; m < 64; m <<= 1) acc += __shfl_xor(acc, m);
    if (l == 0) tgt[wid] = acc + out_b[tg];
}

__global__ __launch_bounds__(256) void stats_reduce(const float* __restrict__ stats, const float* __restrict__ tgt,
                                                    const int* __restrict__ ts, float* __restrict__ sums) {
    int r = blockIdx.x * 256 + threadIdx.x;
    float nll = 0.f, mk = 0.f;
    if (r < MDEC) {
        float M = -1e30f, S = 0.f;
        for (int cb = 0; cb < NCB; ++cb) {
            float m = stats[((size_t)cb * MDEC + r) * 2];
            float s = stats[((size_t)cb * MDEC + r) * 2 + 1];
            if (m > M) { S = S * __expf(M - m) + s; M = m; }
            else { S += s * __expf(m - M); }
        }
        float logZ = M + __logf(S);
        int t = r >> 6, b = r & 63;
        int tg = ts[(t + 1) * NB + b];
        mk = (tg != 0) ? 1.f : 0.f;
        nll = (logZ - tgt[r]) * mk;
    }
#pragma unroll
    for (int m = 1; m < 64; m <<= 1) { nll += __shfl_xor(nll, m); mk += __shfl_xor(mk, m); }
    if ((threadIdx.x & 63) == 0) { atomicAdd(&sums[0], nll); atomicAdd(&sums[1], mk); }
}

__global__ void final_div(const float* __restrict__ sums, float* __restrict__ out) { out[0] = sums[0] / sums[1]; }

// ==================== host ====================
extern "C" void kernel_launch(void* const* d_in, const int* in_sizes, int n_in,
                              void* d_out, int out_size, void* d_ws, size_t ws_size,
                              hipStream_t stream) {
    const int* xs = (const int*)d_in[0];
    const int* ts = (const int*)d_in[1];
    const float* src_emb = (const float*)d_in[2];
    const float* tgt_emb = (const float*)d_in[3];
    const float* encf_Wih = (const float*)d_in[4];
    const float* encf_Whh = (const float*)d_in[5];
    const float* encf_bih = (const float*)d_in[6];
    const float* encf_bhh = (const float*)d_in[7];
    const float* encb_Wih = (const float*)d_in[8];
    const float* encb_Whh = (const float*)d_in[9];
    const float* encb_bih = (const float*)d_in[10];
    const float* encb_bhh = (const float*)d_in[11];
    const float* dec_Wih = (const float*)d_in[12];
    const float* dec_Whh = (const float*)d_in[13];
    const float* dec_bih = (const float*)d_in[14];
    const float* dec_bhh = (const float*)d_in[15];
    const float* attn_W = (const float*)d_in[16];
    const float* attn_v = (const float*)d_in[17];
    const float* lin_W = (const float*)d_in[18];
    const float* lin_b = (const float*)d_in[19];
    const float* out_W = (const float*)d_in[20];
    const float* out_b = (const float*)d_in[21];

    char* p = (char*)d_ws;
    auto alloc = [&](size_t bytes) { void* r = (void*)p; p += (bytes + 255) & ~(size_t)255; return r; };

    // zero zone (contiguous): hencA(2 dirs) + hdec0 + od_bf + sums
    us* hencA = (us*)alloc(2 * NB * 512 * 2);
    us* hdec0 = (us*)alloc(NB * 512 * 2);
    us* od_bf = (us*)alloc(NB * 512 * 2);
    float* sums = (float*)alloc(2 * 4);
    const int ZN = (2 * NB * 512 * 2 + NB * 512 * 2 + NB * 512 * 2 + 256) / 4;

    us* hencB = (us*)alloc(2 * NB * 512 * 2);
    us* hdec1 = (us*)alloc(NB * 512 * 2);
    us* ctx_bf = (us*)alloc(NB * 1024 * 2);
    float* qbuf = (float*)alloc((size_t)NB * 1024 * 4);
    float* scores = (float*)alloc(48 * 64 * 4);
    float* stats = (float*)alloc((size_t)NCB * MDEC * 2 * 4);
    float* tgtl = (float*)alloc((size_t)MDEC * 4);

    us* wcomb_pbf = (us*)alloc((size_t)G * 1024 * 2);
    us* whhf_pbf = (us*)alloc((size_t)G * 512 * 2);
    us* whhb_pbf = (us*)alloc((size_t)G * 512 * 2);
    us* embs_bf = (us*)alloc((size_t)MENC * E * 2);
    us* tembs_bf = (us*)alloc((size_t)MDEC * E * 2);
    us* wfih_bf = (us*)alloc((size_t)G * 512 * 2);
    us* wbih_bf = (us*)alloc((size_t)G * 512 * 2);
    us* wdE_bf = (us*)alloc((size_t)G * 512 * 2);
    us* wk_bf = (us*)alloc((size_t)1024 * 1024 * 2);
    us* linw_bf = (us*)alloc((size_t)512 * 1536 * 2);
    us* wout_bf = (us*)alloc((size_t)V * 512 * 2);
    us* gxf_bf = (us*)alloc((size_t)MENC * G * 2);
    us* gxb_bf = (us*)alloc((size_t)MENC * G * 2);
    us* gemb_bf = (us*)alloc((size_t)MDEC * G * 2);
    us* hs_bf = (us*)alloc((size_t)MENC * 1024 * 2);
    us* hsproj_bf = (us*)alloc((size_t)MENC * 1024 * 2);
    us* hdec_bf = (us*)alloc((size_t)MDEC * 512 * 2);

    zero_k<<<dim3((ZN + 255) / 256), 256, 0, stream>>>((float*)hencA, ZN);

    conv_bf16<<<dim3((G * 512 + 255) / 256), 256, 0, stream>>>(encf_Wih, 512, 0, wfih_bf, G, 512);
    conv_bf16<<<dim3((G * 512 + 255) / 256), 256, 0, stream>>>(encb_Wih, 512, 0, wbih_bf, G, 512);
    conv_bf16<<<dim3((G * 512 + 255) / 256), 256, 0, stream>>>(dec_Wih, 1024, 0, wdE_bf, G, 512);
    conv_bf16<<<dim3((1024 * 1024 + 255) / 256), 256, 0, stream>>>(attn_W, 1536, 512, wk_bf, 1024, 1024);
    conv_bf16<<<dim3((512 * 1536 + 255) / 256), 256, 0, stream>>>(lin_W, 1536, 0, linw_bf, 512, 1536);
    conv_bf16<<<dim3((V * 512 + 255) / 256), 256, 0, stream>>>(out_W, 512, 0, wout_bf, V, 512);
    pack_wcomb_bf<<<dim3(G * 1024 / 256), 256, 0, stream>>>(dec_Wih, dec_Whh, wcomb_pbf);
    pack_whh_bf<<<dim3(G * 512 / 256), 256, 0, stream>>>(encf_Whh, whhf_pbf);
    pack_whh_bf<<<dim3(G * 512 / 256), 256, 0, stream>>>(encb_Whh, whhb_pbf);

    gather_bf16<<<dim3(MENC), 256, 0, stream>>>(xs, src_emb, embs_bf);
    gather_bf16<<<dim3(MDEC), 256, 0, stream>>>(ts, tgt_emb, tembs_bf);

    gemm16<1><<<dim3(G / 64, MENC / 64), 256, 0, stream>>>(embs_bf, 512, wfih_bf, 512, encf_bih, encf_bhh, gxf_bf, G, 512, 0);
    gemm16<1><<<dim3(G / 64, MENC / 64), 256, 0, stream>>>(embs_bf, 512, wbih_bf, 512, encb_bih, encb_bhh, gxb_bf, G, 512, 0);
    gemm16<1><<<dim3(G / 64, MDEC / 64), 256, 0, stream>>>(tembs_bf, 512, wdE_bf, 512, dec_bih, dec_bhh, gemb_bf, G, 512, 0);

    // persistent encoder
    {
        const us* a0 = gxf_bf; const us* a1 = gxb_bf;
        const us* a2 = whhf_pbf; const us* a3 = whhb_pbf;
        us* a4 = hencA; us* a5 = hencB;
        us* a6 = hs_bf;
        void* args[] = { &a0, &a1, &a2, &a3, &a4, &a5, &a6 };
        hipLaunchCooperativeKernel((void*)enc_coop2, dim3(256), dim3(256), args, 0, stream);
    }

    gemm16<1><<<dim3(1024 / 64, MENC / 64), 256, 0, stream>>>(hs_bf, 1024, wk_bf, 1024, nullptr, nullptr, hsproj_bf, 1024, 1024, 0);

    // persistent decoder
    {
        const us* a0 = gemb_bf; const us* a1 = wcomb_pbf;
        const float* a2 = attn_W; const float* a3 = attn_v;
        const us* a4 = hsproj_bf; const us* a5 = hs_bf;
        const us* a6 = linw_bf; const float* a7 = lin_b;
        us* a8 = hdec0; us* a9 = hdec1;
        us* a10 = od_bf; float* a11 = qbuf;
        float* a12 = scores; us* a13 = ctx_bf;
        us* a14 = hdec_bf;
        void* args[] = { &a0, &a1, &a2, &a3, &a4, &a5, &a6, &a7, &a8, &a9, &a10, &a11, &a12, &a13, &a14 };
        hipLaunchCooperativeKernel((void*)dec_coop2, dim3(256), dim3(256), args, 0, stream);
    }

    gemm16<2><<<dim3(NCB, MDEC / 64), 256, 0, stream>>>(hdec_bf, 512, wout_bf, 512, out_b, nullptr, stats, 0, 512, MDEC);

    tgt_kernel<<<dim3(MDEC / 4), 256, 0, stream>>>(hdec_bf, wout_bf, out_b, ts, tgtl);
    stats_reduce<<<dim3((MDEC + 255) / 256), 256, 0, stream>>>(stats, tgtl, ts, sums);
    final_div<<<dim3(1), 1, 0, stream>>>(sums, (float*)d_out);
}

// Round 4
// 6412.411 us; speedup vs baseline: 1.8669x; 1.8669x over previous
//
#include <hip/hip_runtime.h>
#include <stdint.h>

typedef unsigned short us;
typedef __attribute__((ext_vector_type(8))) short bf16x8;
typedef __attribute__((ext_vector_type(4))) float f32x4;

#define DI __device__ __forceinline__

constexpr int LS = 48, LT = 48, NB = 64, E = 512, G = 2048, V = 32000;
constexpr int TD = LT - 1;       // 47 decoder steps
constexpr int MENC = LS * NB;    // 3072
constexpr int MDEC = TD * NB;    // 3008
constexpr int NCB = V / 64;      // 500 column blocks for logits stats

DI float bf2f(us u) { union { unsigned int i; float f; } c; c.i = ((unsigned int)u) << 16; return c.f; }
DI us f2bf(float f) { union { float f; unsigned int i; } c; c.f = f; return (us)((c.i + 0x7fffu + ((c.i >> 16) & 1u)) >> 16); }
DI float sigm(float x) { return 1.f / (1.f + __expf(-x)); }
DI float tanh_(float x) { x = fminf(15.f, fmaxf(-15.f, x)); float e = __expf(2.f * x); return (e - 1.f) / (e + 1.f); }

// ---- lightweight grid barrier (replaces ~40us gg.sync) ----
// cnt and gen are 128B apart; generation-based, reset by last arriver.
DI void fastbar(unsigned* cnt, unsigned* gen, unsigned nb) {
    __syncthreads();
    if (threadIdx.x == 0) {
        __builtin_amdgcn_fence(__ATOMIC_RELEASE, "agent");   // wb prior stores to coherent point
        unsigned g = __hip_atomic_load(gen, __ATOMIC_RELAXED, __HIP_MEMORY_SCOPE_AGENT);
        unsigned arrived = __hip_atomic_fetch_add(cnt, 1u, __ATOMIC_RELAXED, __HIP_MEMORY_SCOPE_AGENT);
        if (arrived == nb - 1u) {
            __hip_atomic_store(cnt, 0u, __ATOMIC_RELAXED, __HIP_MEMORY_SCOPE_AGENT);
            __hip_atomic_store(gen, g + 1u, __ATOMIC_RELEASE, __HIP_MEMORY_SCOPE_AGENT); // orders cnt reset before gen bump
        } else {
            while (__hip_atomic_load(gen, __ATOMIC_RELAXED, __HIP_MEMORY_SCOPE_AGENT) == g)
                __builtin_amdgcn_s_sleep(1);
        }
        __builtin_amdgcn_fence(__ATOMIC_ACQUIRE, "agent");   // invalidate so next loads see fresh data
    }
    __syncthreads();
}

// ---------------- utility kernels ----------------
__global__ __launch_bounds__(256) void zero_k(float* p, int n) {
    int i = blockIdx.x * 256 + threadIdx.x;
    if (i < n) p[i] = 0.f;
}

__global__ __launch_bounds__(256) void conv_bf16(const float* __restrict__ src, int lds, int coff,
                                                 us* __restrict__ dst, int rows, int cols) {
    int i = blockIdx.x * 256 + threadIdx.x;
    if (i >= rows * cols) return;
    int r = i / cols, c = i % cols;
    dst[i] = f2bf(src[(size_t)r * lds + coff + c]);
}

__global__ __launch_bounds__(256) void gather_bf16(const int* __restrict__ idx, const float* __restrict__ emb,
                                                   us* __restrict__ dst) {
    int r = blockIdx.x;
    int id = idx[r];
    const float* s = emb + (size_t)id * E;
    us* d = dst + (size_t)r * E;
    for (int c = threadIdx.x; c < E; c += 256) d[c] = f2bf(s[c]);
}

// permuted bf16 pack: out[(j*4+g)][c] ; c<512 -> Wih[g*512+j][512+c], else Whh[g*512+j][c-512]
__global__ __launch_bounds__(256) void pack_wcomb_bf(const float* __restrict__ Wih, const float* __restrict__ Whh,
                                                     us* __restrict__ out) {
    int i = blockIdx.x * 256 + threadIdx.x;  // 2048*1024
    int rp = i >> 10, c = i & 1023;
    int j = rp >> 2, g = rp & 3;
    int orig = g * 512 + j;
    float v = (c < 512) ? Wih[(size_t)orig * 1024 + 512 + c] : Whh[(size_t)orig * 512 + (c - 512)];
    out[i] = f2bf(v);
}

// permuted bf16 pack: out[(j*4+g)][c] = Whh[g*512+j][c]
__global__ __launch_bounds__(256) void pack_whh_bf(const float* __restrict__ Whh, us* __restrict__ out) {
    int i = blockIdx.x * 256 + threadIdx.x;  // 2048*512
    int rp = i >> 9, c = i & 511;
    int j = rp >> 2, g = rp & 3;
    out[i] = f2bf(Whh[(size_t)(g * 512 + j) * 512 + c]);
}

// ---------------- bf16 MFMA GEMM: C[M][N] = A[M][K] @ W[N][K]^T (+bias) ----------------
template <int EPI>
__global__ __launch_bounds__(256) void gemm16(const us* __restrict__ A, int lda,
                                              const us* __restrict__ W, int ldw,
                                              const float* __restrict__ b1, const float* __restrict__ b2,
                                              void* __restrict__ outp, int ldc, int K, int Mrows) {
    __shared__ us As[64][40];
    __shared__ us Ws[64][40];
    const int tid = threadIdx.x;
    const int m0 = blockIdx.y << 6, n0 = blockIdx.x << 6;
    const int srow = tid >> 2, sk = (tid & 3) << 3;
    const int l = tid & 63, w = tid >> 6;
    const int la = l & 15, lb = l >> 4;
    f32x4 acc[4] = {};
    const us* Aptr = A + (size_t)(m0 + srow) * lda + sk;
    const us* Wptr = W + (size_t)(n0 + srow) * ldw + sk;
    for (int k0 = 0; k0 < K; k0 += 32) {
        *(uint4*)&As[srow][sk] = *(const uint4*)(Aptr + k0);
        *(uint4*)&Ws[srow][sk] = *(const uint4*)(Wptr + k0);
        __syncthreads();
        bf16x8 af = *(bf16x8*)&As[(w << 4) + la][lb << 3];
#pragma unroll
        for (int c = 0; c < 4; c++) {
            bf16x8 bw = *(bf16x8*)&Ws[(c << 4) + la][lb << 3];
            acc[c] = __builtin_amdgcn_mfma_f32_16x16x32_bf16(af, bw, acc[c], 0, 0, 0);
        }
        __syncthreads();
    }
    if (EPI == 1) {
        us* O = (us*)outp;
#pragma unroll
        for (int c = 0; c < 4; c++) {
            int col = n0 + (c << 4) + la;
            float badd = (b1 ? b1[col] : 0.f) + (b2 ? b2[col] : 0.f);
#pragma unroll
            for (int r = 0; r < 4; r++) {
                int row = m0 + (w << 4) + (lb << 2) + r;
                O[(size_t)row * ldc + col] = f2bf(acc[c][r] + badd);
            }
        }
    } else {
        float* S = (float*)outp;
        float x[4][4];
#pragma unroll
        for (int c = 0; c < 4; c++) {
            int col = n0 + (c << 4) + la;
            float badd = b1[col];
#pragma unroll
            for (int r = 0; r < 4; r++) x[c][r] = acc[c][r] + badd;
        }
#pragma unroll
        for (int r = 0; r < 4; r++) {
            float lm = fmaxf(fmaxf(x[0][r], x[1][r]), fmaxf(x[2][r], x[3][r]));
#pragma unroll
            for (int mk = 1; mk < 16; mk <<= 1) lm = fmaxf(lm, __shfl_xor(lm, mk));
            float ls = __expf(x[0][r] - lm) + __expf(x[1][r] - lm) + __expf(x[2][r] - lm) + __expf(x[3][r] - lm);
#pragma unroll
            for (int mk = 1; mk < 16; mk <<= 1) ls += __shfl_xor(ls, mk);
            if (la == 0) {
                int row = m0 + (w << 4) + (lb << 2) + r;
                size_t o = ((size_t)blockIdx.x * Mrows + row) * 2;
                S[o] = lm;
                S[o + 1] = ls;
            }
        }
    }
}

// ---------------- persistent encoder: Whh fragments in registers, 1 fastbar/step ----------------
__global__ __launch_bounds__(256, 1) void enc_coop2(const us* __restrict__ gxf, const us* __restrict__ gxb,
                                                    const us* __restrict__ whhf_p, const us* __restrict__ whhb_p,
                                                    us* __restrict__ hA, us* __restrict__ hB,
                                                    us* __restrict__ hs_bf, unsigned* __restrict__ bars) {
    unsigned* bcnt = bars + 0; unsigned* bgen = bars + 32;
    const int bx = blockIdx.x, tid = threadIdx.x;
    const int dir = bx >> 7, lbx = bx & 127;
    const int n0 = lbx * 16, j0 = lbx * 4;
    const us* gx = dir ? gxb : gxf;
    const us* whp = dir ? whhb_p : whhf_p;
    const int l = tid & 63, w = tid >> 6;
    const int arow = w * 16 + (l & 15);
    const int koff = (l >> 4) * 8;
    __shared__ float gbuf[64 * 17];
    bf16x8 wfrag[16];
#pragma unroll
    for (int k0 = 0; k0 < 16; ++k0)
        wfrag[k0] = *(const bf16x8*)&whp[(size_t)(n0 + (l & 15)) * 512 + k0 * 32 + koff];
    const int cb = tid & 63, cjj = tid >> 6;
    const int j = j0 + cjj;
    float cstate = 0.f;
    const size_t dof = (size_t)dir * NB * 512;
    for (int s = 0; s < LS; ++s) {
        const us* hprev = ((s & 1) ? hB : hA) + dof;
        us* hcur = (us*)(((s & 1) ? hA : hB) + dof);
        const int lrow = dir ? (LS - 1 - s) : s;
        f32x4 acc = {0.f, 0.f, 0.f, 0.f};
#pragma unroll
        for (int k0 = 0; k0 < 16; ++k0) {
            bf16x8 af = *(const bf16x8*)&hprev[(size_t)arow * 512 + k0 * 32 + koff];
            acc = __builtin_amdgcn_mfma_f32_16x16x32_bf16(af, wfrag[k0], acc, 0, 0, 0);
        }
#pragma unroll
        for (int r = 0; r < 4; ++r) gbuf[(w * 16 + (l >> 4) * 4 + r) * 17 + (l & 15)] = acc[r];
        __syncthreads();
        {
            const us* grow = gx + ((size_t)lrow * NB + cb) * G;
            float ai = gbuf[cb * 17 + cjj * 4 + 0] + bf2f(grow[j]);
            float af_ = gbuf[cb * 17 + cjj * 4 + 1] + bf2f(grow[512 + j]);
            float ag = gbuf[cb * 17 + cjj * 4 + 2] + bf2f(grow[1024 + j]);
            float ao = gbuf[cb * 17 + cjj * 4 + 3] + bf2f(grow[1536 + j]);
            float cn = sigm(af_) * cstate + sigm(ai) * tanh_(ag);
            float hn = sigm(ao) * tanh_(cn);
            cstate = cn;
            us hb = f2bf(hn);
            hcur[(size_t)cb * 512 + j] = hb;
            hs_bf[((size_t)lrow * NB + cb) * 1024 + dir * 512 + j] = hb;
        }
        fastbar(bcnt, bgen, 256);
    }
}

// ---------------- persistent decoder: all step-invariant data in LDS/registers, 5 fastbars/step ----------------
__global__ __launch_bounds__(256, 1) void dec_coop2(
    const us* __restrict__ gemb, const us* __restrict__ wcomb_p,
    const float* __restrict__ attn_W, const float* __restrict__ attn_v,
    const us* __restrict__ hsproj, const us* __restrict__ hs_bf,
    const us* __restrict__ linw_bf, const float* __restrict__ lin_b,
    us* __restrict__ h0, us* __restrict__ h1,
    us* __restrict__ od_bf, float* __restrict__ qbuf,
    float* __restrict__ scores, us* __restrict__ ctx_bf,
    us* __restrict__ hdec_bf, unsigned* __restrict__ bars) {
    unsigned* bcnt = bars + 64; unsigned* bgen = bars + 96;
    __shared__ __align__(16) char smem[111360];
    const int bx = blockIdx.x, tid = threadIdx.x;
    const int l = tid & 63, w = tid >> 6;
    const bool isA = bx < 128;

    // A-path LDS
    us* hs_s = (us*)smem;                         // [48*512]
    float* gbuf = (float*)(smem + 49152);         // [64*17]
    float* pls = (float*)(smem + 49152 + 4352);   // [48]
    // B-path LDS
    us* hsproj_s = (us*)smem;                     // [24*1032]
    us* linw_s = (us*)(smem + 49536);             // [4*1544]
    us* stage = (us*)(smem + 49536 + 12352);      // [32*520] or [16*1544]

    bf16x8 wfrag[32];
    float cstate = 0.f;
    float wqreg[16];
    float vv[16];
    float linb_reg = 0.f;
    const int bB = bx - 128;
    // A ids
    const int arow = w * 16 + (l & 15), koff = (l >> 4) * 8;
    const int n0A = bx * 16;
    const int cb = tid & 63, cjj = tid >> 6;
    const int jA = bx * 4 + cjj;
    // E ids
    const int eb = bx >> 1, edh = bx & 1;
    // B ids
    const int qn = tid >> 5, qkq = tid & 31;
    // C ids
    const int lgrp = bB >> 5, bpair = bB & 31;
    // F ids
    const int fb = tid & 15, fkq = (tid >> 4) & 3, fd = tid >> 6;
    const int d0F = bB * 4;

    if (isA) {
#pragma unroll
        for (int k0 = 0; k0 < 32; ++k0)
            wfrag[k0] = *(const bf16x8*)&wcomb_p[(size_t)(n0A + (l & 15)) * 1024 + k0 * 32 + koff];
        for (int idx = tid; idx < 48 * 64; idx += 256) {
            int r = idx >> 6, c8 = (idx & 63) * 8;
            *(uint4*)&hs_s[r * 512 + c8] = *(const uint4*)&hs_bf[((size_t)r * NB + eb) * 1024 + edh * 512 + c8];
        }
    } else {
        for (int idx = tid; idx < 24 * 128; idx += 256) {
            int r = idx >> 7, c8 = (idx & 127) * 8;
            int lp = r >> 1, bp = r & 1;
            *(uint4*)&hsproj_s[r * 1032 + c8] =
                *(const uint4*)&hsproj[((size_t)(lgrp * 12 + lp) * NB + (bpair * 2 + bp)) * 1024 + c8];
        }
        for (int idx = tid; idx < 4 * 192; idx += 256) {
            int r = idx / 192, c8 = (idx % 192) * 8;
            *(uint4*)&linw_s[r * 1544 + c8] = *(const uint4*)&linw_bf[(size_t)(d0F + r) * 1536 + c8];
        }
#pragma unroll
        for (int m = 0; m < 4; ++m)
            *(float4*)&wqreg[m * 4] = *(const float4*)&attn_W[(size_t)(bB * 8 + qn) * 1536 + qkq * 4 + m * 128];
#pragma unroll
        for (int m = 0; m < 4; ++m)
            *(float4*)&vv[m * 4] = *(const float4*)&attn_v[l * 4 + m * 256];
        linb_reg = lin_b[d0F + fd];
    }
    __syncthreads();

    for (int t = 0; t < TD; ++t) {
        const us* hprev = (t & 1) ? h1 : h0;
        us* hcur = (t & 1) ? h0 : h1;
        // ---- phase A: LSTM cell via MFMA (A-blocks) ----
        if (isA) {
            f32x4 acc = {0.f, 0.f, 0.f, 0.f};
#pragma unroll
            for (int k0 = 0; k0 < 32; ++k0) {
                const us* src = (k0 < 16) ? od_bf : hprev;
                int kk = (k0 & 15) * 32;
                bf16x8 af = *(const bf16x8*)&src[(size_t)arow * 512 + kk + koff];
                acc = __builtin_amdgcn_mfma_f32_16x16x32_bf16(af, wfrag[k0], acc, 0, 0, 0);
            }
#pragma unroll
            for (int r = 0; r < 4; ++r) gbuf[(w * 16 + (l >> 4) * 4 + r) * 17 + (l & 15)] = acc[r];
            __syncthreads();
            {
                const us* grow = gemb + ((size_t)t * NB + cb) * G;
                float ai = gbuf[cb * 17 + cjj * 4 + 0] + bf2f(grow[jA]);
                float af_ = gbuf[cb * 17 + cjj * 4 + 1] + bf2f(grow[512 + jA]);
                float ag = gbuf[cb * 17 + cjj * 4 + 2] + bf2f(grow[1024 + jA]);
                float ao = gbuf[cb * 17 + cjj * 4 + 3] + bf2f(grow[1536 + jA]);
                float cn = sigm(af_) * cstate + sigm(ai) * tanh_(ag);
                float hn = sigm(ao) * tanh_(cn);
                cstate = cn;
                us hb = f2bf(hn);
                hcur[(size_t)cb * 512 + jA] = hb;
                hdec_bf[((size_t)t * NB + cb) * 512 + jA] = hb;
            }
            __syncthreads();
        }
        fastbar(bcnt, bgen, 256);
        if (t == TD - 1) break;
        // ---- phase B: q = h @ Wq^T (B-blocks) ----
        if (!isA) {
            for (int tile = 0; tile < 2; ++tile) {
                for (int idx = tid; idx < 32 * 64; idx += 256) {
                    int r = idx >> 6, c8 = (idx & 63) * 8;
                    *(uint4*)&stage[r * 520 + c8] = *(const uint4*)&hcur[(size_t)(tile * 32 + r) * 512 + c8];
                }
                __syncthreads();
                for (int b = 0; b < 32; ++b) {
                    float acc = 0.f;
#pragma unroll
                    for (int m = 0; m < 4; ++m) {
                        ushort4 hv = *(const ushort4*)&stage[b * 520 + qkq * 4 + m * 128];
                        acc += wqreg[m * 4 + 0] * bf2f(hv.x) + wqreg[m * 4 + 1] * bf2f(hv.y)
                             + wqreg[m * 4 + 2] * bf2f(hv.z) + wqreg[m * 4 + 3] * bf2f(hv.w);
                    }
#pragma unroll
                    for (int mk = 1; mk < 32; mk <<= 1) acc += __shfl_xor(acc, mk);
                    if (qkq == 0) qbuf[(size_t)(tile * 32 + b) * 1024 + bB * 8 + qn] = acc;
                }
                __syncthreads();
            }
        }
        fastbar(bcnt, bgen, 256);
        // ---- phase C: scores (B-blocks) ----
        if (!isA) {
            float qv[2][16];
#pragma unroll
            for (int bp = 0; bp < 2; ++bp)
#pragma unroll
                for (int m = 0; m < 4; ++m)
                    *(float4*)&qv[bp][m * 4] = *(const float4*)&qbuf[(size_t)(bpair * 2 + bp) * 1024 + l * 4 + m * 256];
            for (int pi = 0; pi < 6; ++pi) {
                int pr = w * 6 + pi;
                int lp = pr >> 1, bp = pr & 1;
                float p = 0.f;
#pragma unroll
                for (int m = 0; m < 4; ++m) {
                    ushort4 hv = *(const ushort4*)&hsproj_s[pr * 1032 + l * 4 + m * 256];
                    p += vv[m * 4 + 0] * tanh_(bf2f(hv.x) + qv[bp][m * 4 + 0]);
                    p += vv[m * 4 + 1] * tanh_(bf2f(hv.y) + qv[bp][m * 4 + 1]);
                    p += vv[m * 4 + 2] * tanh_(bf2f(hv.z) + qv[bp][m * 4 + 2]);
                    p += vv[m * 4 + 3] * tanh_(bf2f(hv.w) + qv[bp][m * 4 + 3]);
                }
#pragma unroll
                for (int mk = 1; mk < 64; mk <<= 1) p += __shfl_xor(p, mk);
                if (l == 0) scores[(lgrp * 12 + lp) * 64 + bpair * 2 + bp] = p;
            }
        }
        fastbar(bcnt, bgen, 256);
        // ---- phase E: softmax + context (A-blocks) ----
        if (isA) {
            if (tid < 64) {
                float x = (l < 48) ? scores[l * 64 + eb] : -1e30f;
                float mx = x;
#pragma unroll
                for (int mk = 1; mk < 64; mk <<= 1) mx = fmaxf(mx, __shfl_xor(mx, mk));
                float e = (l < 48) ? __expf(x - mx) : 0.f;
                float s = e;
#pragma unroll
                for (int mk = 1; mk < 64; mk <<= 1) s += __shfl_xor(s, mk);
                if (l < 48) pls[l] = e / s;
            }
            __syncthreads();
            float a0 = 0.f, a1 = 0.f;
            for (int li = 0; li < 48; ++li) {
                float pw = pls[li];
                unsigned int hv = *(const unsigned int*)&hs_s[li * 512 + tid * 2];
                a0 += pw * bf2f((us)(hv & 0xffffu));
                a1 += pw * bf2f((us)(hv >> 16));
            }
            unsigned int outw = (unsigned int)f2bf(a0) | ((unsigned int)f2bf(a1) << 16);
            *(unsigned int*)&ctx_bf[(size_t)eb * 1024 + edh * 512 + tid * 2] = outw;
            __syncthreads();
        }
        fastbar(bcnt, bgen, 256);
        // ---- phase F: o = tanh([c;h] @ lin_W^T + b) (B-blocks) ----
        if (!isA) {
            for (int tile = 0; tile < 4; ++tile) {
                for (int idx = tid; idx < 16 * 192; idx += 256) {
                    int r = idx / 192, c8 = (idx % 192) * 8;
                    const us* src = (c8 < 1024) ? &ctx_bf[(size_t)(tile * 16 + r) * 1024 + c8]
                                                : &hcur[(size_t)(tile * 16 + r) * 512 + (c8 - 1024)];
                    *(uint4*)&stage[r * 1544 + c8] = *(const uint4*)src;
                }
                __syncthreads();
                float acc = 0.f;
#pragma unroll 8
                for (int m = 0; m < 96; ++m) {
                    int k = fkq * 4 + m * 16;
                    ushort4 hv = *(const ushort4*)&stage[fb * 1544 + k];
                    ushort4 wv = *(const ushort4*)&linw_s[fd * 1544 + k];
                    acc += bf2f(hv.x) * bf2f(wv.x) + bf2f(hv.y) * bf2f(wv.y)
                         + bf2f(hv.z) * bf2f(wv.z) + bf2f(hv.w) * bf2f(wv.w);
                }
                acc += __shfl_xor(acc, 16);
                acc += __shfl_xor(acc, 32);
                if (fkq == 0) {
                    float o = tanh_(acc + linb_reg);
                    od_bf[(size_t)(tile * 16 + fb) * 512 + d0F + fd] = f2bf(o);
                }
                __syncthreads();
            }
        }
        fastbar(bcnt, bgen, 256);
    }
}

// ---------------- target logit: one wave per (t,b) row ----------------
__global__ __launch_bounds__(256) void tgt_kernel(const us* __restrict__ hdec_bf, const us* __restrict__ woutbf,
                                                  const float* __restrict__ out_b, const int* __restrict__ ts,
                                                  float* __restrict__ tgt) {
    int wid = blockIdx.x * 4 + (threadIdx.x >> 6);
    int l = threadIdx.x & 63;
    int t = wid >> 6, b = wid & 63;
    int tg = ts[(t + 1) * NB + b];
    const us* hr = hdec_bf + (size_t)wid * 512 + l * 8;
    const us* wr = woutbf + (size_t)tg * 512 + l * 8;
    float acc = 0.f;
#pragma unroll
    for (int i = 0; i < 8; i++) acc += bf2f(hr[i]) * bf2f(wr[i]);
#pragma unroll
    for (int m = 1; m < 64; m <<= 1) acc += __shfl_xor(acc, m);
    if (l == 0) tgt[wid] = acc + out_b[tg];
}

__global__ __launch_bounds__(256) void stats_reduce(const float* __restrict__ stats, const float* __restrict__ tgt,
                                                    const int* __restrict__ ts, float* __restrict__ sums) {
    int r = blockIdx.x * 256 + threadIdx.x;
    float nll = 0.f, mk = 0.f;
    if (r < MDEC) {
        float M = -1e30f, S = 0.f;
        for (int cb = 0; cb < NCB; ++cb) {
            float m = stats[((size_t)cb * MDEC + r) * 2];
            float s = stats[((size_t)cb * MDEC + r) * 2 + 1];
            if (m > M) { S = S * __expf(M - m) + s; M = m; }
            else { S += s * __expf(m - M); }
        }
        float logZ = M + __logf(S);
        int t = r >> 6, b = r & 63;
        int tg = ts[(t + 1) * NB + b];
        mk = (tg != 0) ? 1.f : 0.f;
        nll = (logZ - tgt[r]) * mk;
    }
#pragma unroll
    for (int m = 1; m < 64; m <<= 1) { nll += __shfl_xor(nll, m); mk += __shfl_xor(mk, m); }
    if ((threadIdx.x & 63) == 0) { atomicAdd(&sums[0], nll); atomicAdd(&sums[1], mk); }
}

__global__ void final_div(const float* __restrict__ sums, float* __restrict__ out) { out[0] = sums[0] / sums[1]; }

// ==================== host ====================
extern "C" void kernel_launch(void* const* d_in, const int* in_sizes, int n_in,
                              void* d_out, int out_size, void* d_ws, size_t ws_size,
                              hipStream_t stream) {
    const int* xs = (const int*)d_in[0];
    const int* ts = (const int*)d_in[1];
    const float* src_emb = (const float*)d_in[2];
    const float* tgt_emb = (const float*)d_in[3];
    const float* encf_Wih = (const float*)d_in[4];
    const float* encf_Whh = (const float*)d_in[5];
    const float* encf_bih = (const float*)d_in[6];
    const float* encf_bhh = (const float*)d_in[7];
    const float* encb_Wih = (const float*)d_in[8];
    const float* encb_Whh = (const float*)d_in[9];
    const float* encb_bih = (const float*)d_in[10];
    const float* encb_bhh = (const float*)d_in[11];
    const float* dec_Wih = (const float*)d_in[12];
    const float* dec_Whh = (const float*)d_in[13];
    const float* dec_bih = (const float*)d_in[14];
    const float* dec_bhh = (const float*)d_in[15];
    const float* attn_W = (const float*)d_in[16];
    const float* attn_v = (const float*)d_in[17];
    const float* lin_W = (const float*)d_in[18];
    const float* lin_b = (const float*)d_in[19];
    const float* out_W = (const float*)d_in[20];
    const float* out_b = (const float*)d_in[21];

    char* p = (char*)d_ws;
    auto alloc = [&](size_t bytes) { void* r = (void*)p; p += (bytes + 255) & ~(size_t)255; return r; };

    // zero zone (contiguous): hencA(2 dirs) + hdec0 + od_bf + sums + barrier words
    us* hencA = (us*)alloc(2 * NB * 512 * 2);     // 131072 B
    us* hdec0 = (us*)alloc(NB * 512 * 2);         // 65536 B
    us* od_bf = (us*)alloc(NB * 512 * 2);         // 65536 B
    float* sums = (float*)alloc(2 * 4);           // 256 B
    unsigned* bars = (unsigned*)alloc(512);       // 512 B: enc cnt@0 gen@32, dec cnt@64 gen@96
    const int ZN = (131072 + 65536 + 65536 + 256 + 512) / 4;

    us* hencB = (us*)alloc(2 * NB * 512 * 2);
    us* hdec1 = (us*)alloc(NB * 512 * 2);
    us* ctx_bf = (us*)alloc(NB * 1024 * 2);
    float* qbuf = (float*)alloc((size_t)NB * 1024 * 4);
    float* scores = (float*)alloc(48 * 64 * 4);
    float* stats = (float*)alloc((size_t)NCB * MDEC * 2 * 4);
    float* tgtl = (float*)alloc((size_t)MDEC * 4);

    us* wcomb_pbf = (us*)alloc((size_t)G * 1024 * 2);
    us* whhf_pbf = (us*)alloc((size_t)G * 512 * 2);
    us* whhb_pbf = (us*)alloc((size_t)G * 512 * 2);
    us* embs_bf = (us*)alloc((size_t)MENC * E * 2);
    us* tembs_bf = (us*)alloc((size_t)MDEC * E * 2);
    us* wfih_bf = (us*)alloc((size_t)G * 512 * 2);
    us* wbih_bf = (us*)alloc((size_t)G * 512 * 2);
    us* wdE_bf = (us*)alloc((size_t)G * 512 * 2);
    us* wk_bf = (us*)alloc((size_t)1024 * 1024 * 2);
    us* linw_bf = (us*)alloc((size_t)512 * 1536 * 2);
    us* wout_bf = (us*)alloc((size_t)V * 512 * 2);
    us* gxf_bf = (us*)alloc((size_t)MENC * G * 2);
    us* gxb_bf = (us*)alloc((size_t)MENC * G * 2);
    us* gemb_bf = (us*)alloc((size_t)MDEC * G * 2);
    us* hs_bf = (us*)alloc((size_t)MENC * 1024 * 2);
    us* hsproj_bf = (us*)alloc((size_t)MENC * 1024 * 2);
    us* hdec_bf = (us*)alloc((size_t)MDEC * 512 * 2);

    zero_k<<<dim3((ZN + 255) / 256), 256, 0, stream>>>((float*)hencA, ZN);

    conv_bf16<<<dim3((G * 512 + 255) / 256), 256, 0, stream>>>(encf_Wih, 512, 0, wfih_bf, G, 512);
    conv_bf16<<<dim3((G * 512 + 255) / 256), 256, 0, stream>>>(encb_Wih, 512, 0, wbih_bf, G, 512);
    conv_bf16<<<dim3((G * 512 + 255) / 256), 256, 0, stream>>>(dec_Wih, 1024, 0, wdE_bf, G, 512);
    conv_bf16<<<dim3((1024 * 1024 + 255) / 256), 256, 0, stream>>>(attn_W, 1536, 512, wk_bf, 1024, 1024);
    conv_bf16<<<dim3((512 * 1536 + 255) / 256), 256, 0, stream>>>(lin_W, 1536, 0, linw_bf, 512, 1536);
    conv_bf16<<<dim3((V * 512 + 255) / 256), 256, 0, stream>>>(out_W, 512, 0, wout_bf, V, 512);
    pack_wcomb_bf<<<dim3(G * 1024 / 256), 256, 0, stream>>>(dec_Wih, dec_Whh, wcomb_pbf);
    pack_whh_bf<<<dim3(G * 512 / 256), 256, 0, stream>>>(encf_Whh, whhf_pbf);
    pack_whh_bf<<<dim3(G * 512 / 256), 256, 0, stream>>>(encb_Whh, whhb_pbf);

    gather_bf16<<<dim3(MENC), 256, 0, stream>>>(xs, src_emb, embs_bf);
    gather_bf16<<<dim3(MDEC), 256, 0, stream>>>(ts, tgt_emb, tembs_bf);

    gemm16<1><<<dim3(G / 64, MENC / 64), 256, 0, stream>>>(embs_bf, 512, wfih_bf, 512, encf_bih, encf_bhh, gxf_bf, G, 512, 0);
    gemm16<1><<<dim3(G / 64, MENC / 64), 256, 0, stream>>>(embs_bf, 512, wbih_bf, 512, encb_bih, encb_bhh, gxb_bf, G, 512, 0);
    gemm16<1><<<dim3(G / 64, MDEC / 64), 256, 0, stream>>>(tembs_bf, 512, wdE_bf, 512, dec_bih, dec_bhh, gemb_bf, G, 512, 0);

    // persistent encoder
    {
        const us* a0 = gxf_bf; const us* a1 = gxb_bf;
        const us* a2 = whhf_pbf; const us* a3 = whhb_pbf;
        us* a4 = hencA; us* a5 = hencB;
        us* a6 = hs_bf; unsigned* a7 = bars;
        void* args[] = { &a0, &a1, &a2, &a3, &a4, &a5, &a6, &a7 };
        hipLaunchCooperativeKernel((void*)enc_coop2, dim3(256), dim3(256), args, 0, stream);
    }

    gemm16<1><<<dim3(1024 / 64, MENC / 64), 256, 0, stream>>>(hs_bf, 1024, wk_bf, 1024, nullptr, nullptr, hsproj_bf, 1024, 1024, 0);

    // persistent decoder
    {
        const us* a0 = gemb_bf; const us* a1 = wcomb_pbf;
        const float* a2 = attn_W; const float* a3 = attn_v;
        const us* a4 = hsproj_bf; const us* a5 = hs_bf;
        const us* a6 = linw_bf; const float* a7 = lin_b;
        us* a8 = hdec0; us* a9 = hdec1;
        us* a10 = od_bf; float* a11 = qbuf;
        float* a12 = scores; us* a13 = ctx_bf;
        us* a14 = hdec_bf; unsigned* a15 = bars;
        void* args[] = { &a0, &a1, &a2, &a3, &a4, &a5, &a6, &a7, &a8, &a9, &a10, &a11, &a12, &a13, &a14, &a15 };
        hipLaunchCooperativeKernel((void*)dec_coop2, dim3(256), dim3(256), args, 0, stream);
    }

    gemm16<2><<<dim3(NCB, MDEC / 64), 256, 0, stream>>>(hdec_bf, 512, wout_bf, 512, out_b, nullptr, stats, 0, 512, MDEC);

    tgt_kernel<<<dim3(MDEC / 4), 256, 0, stream>>>(hdec_bf, wout_bf, out_b, ts, tgtl);
    stats_reduce<<<dim3((MDEC + 255) / 256), 256, 0, stream>>>(stats, tgtl, ts, sums);
    final_div<<<dim3(1), 1, 0, stream>>>(sums, (float*)d_out);
}